// Round 1
// baseline (1108.727 us; speedup 1.0000x reference)
//
#include <hip/hip_runtime.h>
#include <math.h>

#define NRAYS 8192
#define NS 128

// One block per ray, one thread per depth sample.
__global__ __launch_bounds__(NS, 2)
void mpi_render(const float* __restrict__ rays_o,
                const float* __restrict__ rays_d,
                const float* __restrict__ dgrid,   // (256,256,128,1)
                const float* __restrict__ k0g,     // (256,256,128,12)
                const float* __restrict__ ash,     // (128,)
                const float* __restrict__ w0,      // (66,128)
                const float* __restrict__ b0,      // (128,)
                const float* __restrict__ w1,      // (128,128)
                const float* __restrict__ b1,      // (128,)
                const float* __restrict__ w2,      // (128,3)
                const float* __restrict__ b2,      // (3,)
                float* __restrict__ out)           // (8192,3)
{
    const int r = blockIdx.x;
    const int s = threadIdx.x;

    const float ox = rays_o[3*r+0], oy = rays_o[3*r+1], oz = rays_o[3*r+2];
    const float dx = rays_d[3*r+0], dy = rays_d[3*r+1], dz = rays_d[3*r+2];

    const float t  = (float)s * (1.0f/127.0f);
    const float px = fmaf(dx, t, ox);
    const float py = fmaf(dy, t, oy);
    const float pz = fmaf(dz, t, oz);

    // ---- grid coords (shared by both trilerps) ----
    float ux = (px + 1.0f) * (0.5f * 255.0f);
    float uy = (py + 1.0f) * (0.5f * 255.0f);
    float uz = pz * 127.0f;
    ux = fminf(fmaxf(ux, 0.0f), 255.0f);
    uy = fminf(fmaxf(uy, 0.0f), 255.0f);
    uz = fminf(fmaxf(uz, 0.0f), 127.0f);
    int ix = (int)ux; if (ix > 254) ix = 254;
    int iy = (int)uy; if (iy > 254) iy = 254;
    int iz = (int)uz; if (iz > 126) iz = 126;
    const float fx = ux - (float)ix;
    const float fy = uy - (float)iy;
    const float fz = uz - (float)iz;

    const float wx0 = 1.0f - fx, wx1 = fx;
    const float wy0 = 1.0f - fy, wy1 = fy;
    const float wz0 = 1.0f - fz, wz1 = fz;

    const int OX = 256*128, OY = 128;
    const int base = (ix * 256 + iy) * 128 + iz;

    float cw[8];
    cw[0] = wx0*wy0*wz0; cw[1] = wx0*wy0*wz1;
    cw[2] = wx0*wy1*wz0; cw[3] = wx0*wy1*wz1;
    cw[4] = wx1*wy0*wz0; cw[5] = wx1*wy0*wz1;
    cw[6] = wx1*wy1*wz0; cw[7] = wx1*wy1*wz1;
    int cidx[8];
    cidx[0] = base;           cidx[1] = base + 1;
    cidx[2] = base + OY;      cidx[3] = base + OY + 1;
    cidx[4] = base + OX;      cidx[5] = base + OX + 1;
    cidx[6] = base + OX + OY; cidx[7] = base + OX + OY + 1;

    // ---- density trilerp + act_shift lerp + alpha ----
    float dens = 0.0f;
    #pragma unroll
    for (int c = 0; c < 8; ++c) dens = fmaf(cw[c], dgrid[cidx[c]], dens);

    const float shift = wz0 * ash[iz] + fz * ash[iz+1];

    const float dsh = dens + shift;
    const float sp  = fmaxf(dsh, 0.0f) + log1pf(expf(-fabsf(dsh)));  // softplus
    const float alpha = 1.0f - expf(-2.0f * sp);                     // INTERVAL = 2

    // ---- cumprod(1-alpha) via LDS Hillis-Steele scan ----
    __shared__ float s_t[NS];
    __shared__ float s_part[2][4];
    s_t[s] = 1.0f - alpha;
    __syncthreads();
    #pragma unroll
    for (int off = 1; off < NS; off <<= 1) {
        const float v = s_t[s];
        const float p = (s >= off) ? s_t[s - off] : 1.0f;
        __syncthreads();
        s_t[s] = v * p;
        __syncthreads();
    }
    const float tprev = (s == 0) ? 1.0f : s_t[s-1];
    const float wgt   = alpha * tprev;
    const float alast = s_t[NS-1];

    // ---- feature vector: [k0(12) | xemb(27) | vemb(27)] ----
    float feat[66];
    #pragma unroll
    for (int q = 0; q < 12; ++q) feat[q] = 0.0f;
    #pragma unroll
    for (int c = 0; c < 8; ++c) {
        const float4* p4 = reinterpret_cast<const float4*>(k0g + (size_t)cidx[c] * 12);
        const float4 a = p4[0], b = p4[1], d = p4[2];
        const float w = cw[c];
        feat[0] = fmaf(w, a.x, feat[0]); feat[1] = fmaf(w, a.y, feat[1]);
        feat[2] = fmaf(w, a.z, feat[2]); feat[3] = fmaf(w, a.w, feat[3]);
        feat[4] = fmaf(w, b.x, feat[4]); feat[5] = fmaf(w, b.y, feat[5]);
        feat[6] = fmaf(w, b.z, feat[6]); feat[7] = fmaf(w, b.w, feat[7]);
        feat[8] = fmaf(w, d.x, feat[8]); feat[9] = fmaf(w, d.y, feat[9]);
        feat[10]= fmaf(w, d.z, feat[10]);feat[11]= fmaf(w, d.w, feat[11]);
    }

    feat[12] = px; feat[13] = py; feat[14] = pz;
    {
        const float pc[3] = {px, py, pz};
        #pragma unroll
        for (int c = 0; c < 3; ++c) {
            #pragma unroll
            for (int f = 0; f < 4; ++f) {
                float sv, cv;
                sincosf(pc[c] * (float)(1 << f), &sv, &cv);
                feat[15 + c*4 + f] = sv;
                feat[27 + c*4 + f] = cv;
            }
        }
    }
    const float vnorm = sqrtf(dx*dx + dy*dy + dz*dz);
    const float vx = dx / vnorm, vy = dy / vnorm, vz = dz / vnorm;
    feat[39] = vx; feat[40] = vy; feat[41] = vz;
    {
        const float vc[3] = {vx, vy, vz};
        #pragma unroll
        for (int c = 0; c < 3; ++c) {
            #pragma unroll
            for (int f = 0; f < 4; ++f) {
                float sv, cv;
                sincosf(vc[c] * (float)(1 << f), &sv, &cv);
                feat[42 + c*4 + f] = sv;
                feat[54 + c*4 + f] = cv;
            }
        }
    }

    // ---- MLP: layer0 (66->128) interleaved with layer1 rank-1 update (128->128) ----
    float acc1[128];
    #pragma unroll
    for (int k = 0; k < 128; ++k) acc1[k] = b1[k];

    #pragma unroll 1
    for (int j = 0; j < 128; ++j) {
        // 4 partial accumulators to break the dependent-FMA chain
        float a0 = b0[j], a1 = 0.0f, a2 = 0.0f, a3 = 0.0f;
        const float* w0c = w0 + j;        // column j, stride 128
        #pragma unroll
        for (int i = 0; i < 64; i += 4) {
            a0 = fmaf(feat[i+0], w0c[(i+0)*128], a0);
            a1 = fmaf(feat[i+1], w0c[(i+1)*128], a1);
            a2 = fmaf(feat[i+2], w0c[(i+2)*128], a2);
            a3 = fmaf(feat[i+3], w0c[(i+3)*128], a3);
        }
        a0 = fmaf(feat[64], w0c[64*128], a0);
        a1 = fmaf(feat[65], w0c[65*128], a1);
        const float h = fmaxf((a0 + a1) + (a2 + a3), 0.0f);

        const float* w1r = w1 + j * 128;  // row j, contiguous
        #pragma unroll
        for (int k = 0; k < 128; ++k) acc1[k] = fmaf(h, w1r[k], acc1[k]);
    }

    // ---- layer2 (128->3) + sigmoid ----
    float o0 = b2[0], o1 = b2[1], o2 = b2[2];
    #pragma unroll
    for (int k = 0; k < 128; ++k) {
        const float h = fmaxf(acc1[k], 0.0f);
        o0 = fmaf(h, w2[3*k+0], o0);
        o1 = fmaf(h, w2[3*k+1], o1);
        o2 = fmaf(h, w2[3*k+2], o2);
    }
    const float r0 = 1.0f / (1.0f + expf(-o0));
    const float r1 = 1.0f / (1.0f + expf(-o1));
    const float r2 = 1.0f / (1.0f + expf(-o2));

    // ---- weighted compositing reduce over the 128 samples ----
    float c0 = wgt * r0, c1 = wgt * r1, c2 = wgt * r2;
    #pragma unroll
    for (int off = 32; off > 0; off >>= 1) {
        c0 += __shfl_down(c0, off);
        c1 += __shfl_down(c1, off);
        c2 += __shfl_down(c2, off);
    }
    if ((s & 63) == 0) {
        s_part[s >> 6][0] = c0;
        s_part[s >> 6][1] = c1;
        s_part[s >> 6][2] = c2;
    }
    __syncthreads();
    if (s == 0) {
        out[3*r+0] = s_part[0][0] + s_part[1][0] + alast;  // BG = 1.0
        out[3*r+1] = s_part[0][1] + s_part[1][1] + alast;
        out[3*r+2] = s_part[0][2] + s_part[1][2] + alast;
    }
}

extern "C" void kernel_launch(void* const* d_in, const int* in_sizes, int n_in,
                              void* d_out, int out_size, void* d_ws, size_t ws_size,
                              hipStream_t stream) {
    const float* rays_o = (const float*)d_in[0];
    const float* rays_d = (const float*)d_in[1];
    const float* dgrid  = (const float*)d_in[2];
    const float* k0g    = (const float*)d_in[3];
    const float* ash    = (const float*)d_in[4];
    const float* w0     = (const float*)d_in[5];
    const float* b0     = (const float*)d_in[6];
    const float* w1     = (const float*)d_in[7];
    const float* b1     = (const float*)d_in[8];
    const float* w2     = (const float*)d_in[9];
    const float* b2     = (const float*)d_in[10];
    float* out = (float*)d_out;

    mpi_render<<<NRAYS, NS, 0, stream>>>(rays_o, rays_d, dgrid, k0g, ash,
                                         w0, b0, w1, b1, w2, b2, out);
}

// Round 2
// 245.331 us; speedup vs baseline: 4.5193x; 4.5193x over previous
//
#include <hip/hip_runtime.h>
#include <math.h>

#define NRAYS 8192
#define NS 128

typedef short bf16x8 __attribute__((ext_vector_type(8)));
typedef float f32x4  __attribute__((ext_vector_type(4)));

__device__ __host__ __forceinline__ unsigned short f2bf(float f) {
    union { float f; unsigned u; } v; v.f = f;
    unsigned r = v.u + 0x7FFFu + ((v.u >> 16) & 1u);
    return (unsigned short)(r >> 16);
}
__device__ __forceinline__ float bf2f(unsigned short u) {
    union { unsigned u; float f; } v; v.u = ((unsigned)u) << 16;
    return v.f;
}

// ---------------- prep kernel: pack w0/w1 into MFMA B-fragment order ----------------
// Frag f: f<16 -> L0 (ks=f>>3, nt=f&7, K=64, rows>=39 zero); f>=16 -> L1 (ks,nt of f-16).
// Lane l holds B[k=(l>>4)*8+j][n=nt*16+(l&15)], 8 bf16 = 16B at ws[(f*64+l)*16].
__global__ void prep_weights(const float* __restrict__ w0,
                             const float* __restrict__ w1,
                             uint4* __restrict__ wsB)
{
    const int f = blockIdx.x;   // 0..47
    const int l = threadIdx.x;  // 0..63
    const float* W; int kvalid, ks, nt;
    if (f < 16) { ks = f >> 3; nt = f & 7; W = w0; kvalid = 39; }
    else        { int g = f - 16; ks = g >> 3; nt = g & 7; W = w1; kvalid = 128; }
    const int n  = nt * 16 + (l & 15);
    const int kb = ks * 32 + ((l >> 4) << 3);
    unsigned p[4];
    #pragma unroll
    for (int w = 0; w < 4; ++w) {
        int k0i = kb + 2 * w;
        float v0 = (k0i     < kvalid) ? W[(size_t)k0i * 128 + n]       : 0.0f;
        float v1 = (k0i + 1 < kvalid) ? W[(size_t)(k0i + 1) * 128 + n] : 0.0f;
        p[w] = (unsigned)f2bf(v0) | ((unsigned)f2bf(v1) << 16);
    }
    wsB[f * 64 + l] = make_uint4(p[0], p[1], p[2], p[3]);
}

// ---------------- main kernel: one ray per block ----------------
__global__ __launch_bounds__(256, 2)
void mpi_mlp(const float* __restrict__ rays_o,
             const float* __restrict__ rays_d,
             const float* __restrict__ dgrid,   // (256,256,128,1)
             const float* __restrict__ k0g,     // (256,256,128,12)
             const float* __restrict__ ash,     // (128,)
             const float* __restrict__ w0,      // (66,128) rows 39..65 used here
             const float* __restrict__ b0,      // (128,)
             const float* __restrict__ b1,      // (128,)
             const float* __restrict__ w2,      // (128,3)
             const float* __restrict__ b2,      // (3,)
             const uint4* __restrict__ wsB,
             float* __restrict__ out)           // (8192,3)
{
    __shared__ __align__(16) unsigned short sA[128][72];   // feat bf16, K-pad 64 (+8)
    __shared__ __align__(16) unsigned short sH[128][136];  // h0/h1 bf16 (128+8)
    __shared__ float s_scan[128];
    __shared__ float s_wgt[128];
    __shared__ float s_rayh[128];   // b0[n] + vemb·w0[39:66,n]
    __shared__ float s_part[4][3];

    const int t = threadIdx.x;
    const int r = blockIdx.x;

    const float ox = rays_o[3*r+0], oy = rays_o[3*r+1], oz = rays_o[3*r+2];
    const float dx = rays_d[3*r+0], dy = rays_d[3*r+1], dz = rays_d[3*r+2];

    float alpha = 0.0f;   // live across scan for t<128

    if (t < 128) {
        // ---------- gather half: density + k0 trilerp, alpha ----------
        const int p = t;
        const float tp = (float)p * (1.0f/127.0f);
        const float px = fmaf(dx, tp, ox);
        const float py = fmaf(dy, tp, oy);
        const float pz = fmaf(dz, tp, oz);

        float ux = (px + 1.0f) * (0.5f * 255.0f);
        float uy = (py + 1.0f) * (0.5f * 255.0f);
        float uz = pz * 127.0f;
        ux = fminf(fmaxf(ux, 0.0f), 255.0f);
        uy = fminf(fmaxf(uy, 0.0f), 255.0f);
        uz = fminf(fmaxf(uz, 0.0f), 127.0f);
        int ix = (int)ux; if (ix > 254) ix = 254;
        int iy = (int)uy; if (iy > 254) iy = 254;
        int iz = (int)uz; if (iz > 126) iz = 126;
        const float fx = ux - (float)ix;
        const float fy = uy - (float)iy;
        const float fz = uz - (float)iz;
        const float wx0 = 1.0f - fx, wy0 = 1.0f - fy, wz0 = 1.0f - fz;

        const int OX = 256*128, OY = 128;
        const int base = (ix * 256 + iy) * 128 + iz;
        float cw[8]; int cidx[8];
        cw[0]=wx0*wy0*wz0; cw[1]=wx0*wy0*fz; cw[2]=wx0*fy*wz0; cw[3]=wx0*fy*fz;
        cw[4]=fx*wy0*wz0;  cw[5]=fx*wy0*fz;  cw[6]=fx*fy*wz0;  cw[7]=fx*fy*fz;
        cidx[0]=base;        cidx[1]=base+1;
        cidx[2]=base+OY;     cidx[3]=base+OY+1;
        cidx[4]=base+OX;     cidx[5]=base+OX+1;
        cidx[6]=base+OX+OY;  cidx[7]=base+OX+OY+1;

        float dens = 0.0f;
        #pragma unroll
        for (int c = 0; c < 8; ++c) dens = fmaf(cw[c], dgrid[cidx[c]], dens);

        float feat[12];
        #pragma unroll
        for (int q = 0; q < 12; ++q) feat[q] = 0.0f;
        #pragma unroll
        for (int c = 0; c < 8; ++c) {
            const float4* p4 = reinterpret_cast<const float4*>(k0g + (size_t)cidx[c] * 12);
            const float4 a = p4[0], b = p4[1], d = p4[2];
            const float w = cw[c];
            feat[0]=fmaf(w,a.x,feat[0]); feat[1]=fmaf(w,a.y,feat[1]);
            feat[2]=fmaf(w,a.z,feat[2]); feat[3]=fmaf(w,a.w,feat[3]);
            feat[4]=fmaf(w,b.x,feat[4]); feat[5]=fmaf(w,b.y,feat[5]);
            feat[6]=fmaf(w,b.z,feat[6]); feat[7]=fmaf(w,b.w,feat[7]);
            feat[8]=fmaf(w,d.x,feat[8]); feat[9]=fmaf(w,d.y,feat[9]);
            feat[10]=fmaf(w,d.z,feat[10]); feat[11]=fmaf(w,d.w,feat[11]);
        }
        #pragma unroll
        for (int q = 0; q < 6; ++q) {
            unsigned pk = (unsigned)f2bf(feat[2*q]) | ((unsigned)f2bf(feat[2*q+1]) << 16);
            *(unsigned*)&sA[p][2*q] = pk;
        }

        const float shift = wz0 * ash[iz] + fz * ash[iz+1];
        const float dsh = dens + shift;
        const float sp  = fmaxf(dsh, 0.0f) + log1pf(expf(-fabsf(dsh)));
        alpha = 1.0f - expf(-2.0f * sp);     // INTERVAL = 2
        s_scan[p] = 1.0f - alpha;
    } else {
        // ---------- PE half: xemb for point q, vemb fold for column q ----------
        const int q = t - 128;
        const float tp = (float)q * (1.0f/127.0f);
        const float px = fmaf(dx, tp, ox);
        const float py = fmaf(dy, tp, oy);
        const float pz = fmaf(dz, tp, oz);

        sA[q][12] = f2bf(px); sA[q][13] = f2bf(py); sA[q][14] = f2bf(pz);
        {
            const float pc[3] = {px, py, pz};
            #pragma unroll
            for (int c = 0; c < 3; ++c) {
                #pragma unroll
                for (int f = 0; f < 4; ++f) {
                    const float a = pc[c] * (float)(1 << f);
                    sA[q][15 + c*4 + f] = f2bf(__sinf(a));
                    sA[q][27 + c*4 + f] = f2bf(__cosf(a));
                }
            }
        }
        // zero pad cols 39..63
        sA[q][39] = 0;
        #pragma unroll
        for (int c = 0; c < 12; ++c) *(unsigned*)&sA[q][40 + 2*c] = 0u;

        // per-ray vemb (27) folded with w0 rows 39..65 into s_rayh[n], n = q
        const float inv = rsqrtf(dx*dx + dy*dy + dz*dz);
        const float vx = dx*inv, vy = dy*inv, vz = dz*inv;
        float ve[27];
        ve[0] = vx; ve[1] = vy; ve[2] = vz;
        {
            const float vc[3] = {vx, vy, vz};
            #pragma unroll
            for (int c = 0; c < 3; ++c) {
                #pragma unroll
                for (int f = 0; f < 4; ++f) {
                    const float a = vc[c] * (float)(1 << f);
                    ve[3  + c*4 + f] = __sinf(a);
                    ve[15 + c*4 + f] = __cosf(a);
                }
            }
        }
        const int n = q;
        float acc = b0[n];
        #pragma unroll
        for (int i = 0; i < 27; ++i) acc = fmaf(ve[i], w0[(size_t)(39 + i) * 128 + n], acc);
        s_rayh[n] = acc;
    }
    __syncthreads();

    // ---------- cumprod scan over 128 samples (threads 0..127) ----------
    #pragma unroll
    for (int off = 1; off < 128; off <<= 1) {
        float v = 0.0f, pr = 1.0f;
        if (t < 128) { v = s_scan[t]; pr = (t >= off) ? s_scan[t - off] : 1.0f; }
        __syncthreads();
        if (t < 128) s_scan[t] = v * pr;
        __syncthreads();
    }
    if (t < 128) s_wgt[t] = alpha * ((t == 0) ? 1.0f : s_scan[t - 1]);
    __syncthreads();

    // ---------- MFMA layer 0: sA(128x64) @ w0T -> h0(128x128) ----------
    const int wv   = t >> 6;        // wave 0..3, owns rows [wv*32, wv*32+32)
    const int lane = t & 63;
    const int kgrp = lane >> 4;     // 0..3
    const int colb = lane & 15;

    f32x4 C0[2][8];
    #pragma unroll
    for (int mt = 0; mt < 2; ++mt)
        #pragma unroll
        for (int nt = 0; nt < 8; ++nt) C0[mt][nt] = (f32x4){0.f,0.f,0.f,0.f};

    #pragma unroll
    for (int ks = 0; ks < 2; ++ks) {
        bf16x8 B[8];
        #pragma unroll
        for (int nt = 0; nt < 8; ++nt) {
            uint4 raw = wsB[(ks*8 + nt) * 64 + lane];
            B[nt] = *(bf16x8*)&raw;
        }
        #pragma unroll
        for (int mt = 0; mt < 2; ++mt) {
            const int row = wv*32 + mt*16 + colb;
            bf16x8 A = *(const bf16x8*)&sA[row][ks*32 + kgrp*8];
            #pragma unroll
            for (int nt = 0; nt < 8; ++nt)
                C0[mt][nt] = __builtin_amdgcn_mfma_f32_16x16x32_bf16(A, B[nt], C0[mt][nt], 0, 0, 0);
        }
    }

    // h0 = relu(C0 + s_rayh[col]) -> sH (bf16)
    {
        float rh[8];
        #pragma unroll
        for (int nt = 0; nt < 8; ++nt) rh[nt] = s_rayh[nt*16 + colb];
        #pragma unroll
        for (int mt = 0; mt < 2; ++mt)
            #pragma unroll
            for (int nt = 0; nt < 8; ++nt)
                #pragma unroll
                for (int rg = 0; rg < 4; ++rg) {
                    const int row = wv*32 + mt*16 + kgrp*4 + rg;
                    const float v = fmaxf(C0[mt][nt][rg] + rh[nt], 0.0f);
                    sH[row][nt*16 + colb] = f2bf(v);
                }
    }
    __syncthreads();

    // ---------- MFMA layer 1: h0(128x128) @ w1T -> h1(128x128) ----------
    f32x4 C1[2][8];
    #pragma unroll
    for (int mt = 0; mt < 2; ++mt)
        #pragma unroll
        for (int nt = 0; nt < 8; ++nt) C1[mt][nt] = (f32x4){0.f,0.f,0.f,0.f};

    #pragma unroll
    for (int ks = 0; ks < 4; ++ks) {
        bf16x8 B[8];
        #pragma unroll
        for (int nt = 0; nt < 8; ++nt) {
            uint4 raw = wsB[(16 + ks*8 + nt) * 64 + lane];
            B[nt] = *(bf16x8*)&raw;
        }
        #pragma unroll
        for (int mt = 0; mt < 2; ++mt) {
            const int row = wv*32 + mt*16 + colb;
            bf16x8 A = *(const bf16x8*)&sH[row][ks*32 + kgrp*8];
            #pragma unroll
            for (int nt = 0; nt < 8; ++nt)
                C1[mt][nt] = __builtin_amdgcn_mfma_f32_16x16x32_bf16(A, B[nt], C1[mt][nt], 0, 0, 0);
        }
    }
    __syncthreads();   // all waves done reading sH before overwrite

    {
        float bb[8];
        #pragma unroll
        for (int nt = 0; nt < 8; ++nt) bb[nt] = b1[nt*16 + colb];
        #pragma unroll
        for (int mt = 0; mt < 2; ++mt)
            #pragma unroll
            for (int nt = 0; nt < 8; ++nt)
                #pragma unroll
                for (int rg = 0; rg < 4; ++rg) {
                    const int row = wv*32 + mt*16 + kgrp*4 + rg;
                    const float v = fmaxf(C1[mt][nt][rg] + bb[nt], 0.0f);
                    sH[row][nt*16 + colb] = f2bf(v);
                }
    }
    __syncthreads();

    // ---------- layer 2 (128->3) + sigmoid + compositing ----------
    {
        const int p = t >> 1, h = t & 1;
        const int kb = h * 64;
        float o0 = 0.f, o1 = 0.f, o2 = 0.f;
        #pragma unroll
        for (int i = 0; i < 8; ++i) {
            bf16x8 hv = *(const bf16x8*)&sH[p][kb + i*8];
            #pragma unroll
            for (int j = 0; j < 8; ++j) {
                const float hval = bf2f((unsigned short)hv[j]);
                const int k = kb + i*8 + j;
                o0 = fmaf(hval, w2[k*3+0], o0);
                o1 = fmaf(hval, w2[k*3+1], o1);
                o2 = fmaf(hval, w2[k*3+2], o2);
            }
        }
        o0 += __shfl_xor(o0, 1);
        o1 += __shfl_xor(o1, 1);
        o2 += __shfl_xor(o2, 1);
        float c0 = 0.f, c1 = 0.f, c2 = 0.f;
        if (h == 0) {
            const float wg = s_wgt[p];
            c0 = wg / (1.0f + expf(-(o0 + b2[0])));
            c1 = wg / (1.0f + expf(-(o1 + b2[1])));
            c2 = wg / (1.0f + expf(-(o2 + b2[2])));
        }
        #pragma unroll
        for (int off = 2; off <= 32; off <<= 1) {
            c0 += __shfl_down(c0, off);
            c1 += __shfl_down(c1, off);
            c2 += __shfl_down(c2, off);
        }
        if (lane == 0) { s_part[wv][0] = c0; s_part[wv][1] = c1; s_part[wv][2] = c2; }
    }
    __syncthreads();
    if (t == 0) {
        const float alast = s_scan[127];
        out[3*r+0] = s_part[0][0] + s_part[1][0] + s_part[2][0] + s_part[3][0] + alast;
        out[3*r+1] = s_part[0][1] + s_part[1][1] + s_part[2][1] + s_part[3][1] + alast;
        out[3*r+2] = s_part[0][2] + s_part[1][2] + s_part[2][2] + s_part[3][2] + alast;
    }
}

extern "C" void kernel_launch(void* const* d_in, const int* in_sizes, int n_in,
                              void* d_out, int out_size, void* d_ws, size_t ws_size,
                              hipStream_t stream) {
    const float* rays_o = (const float*)d_in[0];
    const float* rays_d = (const float*)d_in[1];
    const float* dgrid  = (const float*)d_in[2];
    const float* k0g    = (const float*)d_in[3];
    const float* ash    = (const float*)d_in[4];
    const float* w0     = (const float*)d_in[5];
    const float* b0     = (const float*)d_in[6];
    const float* w1     = (const float*)d_in[7];
    const float* b1     = (const float*)d_in[8];
    const float* w2     = (const float*)d_in[9];
    const float* b2     = (const float*)d_in[10];
    float* out = (float*)d_out;
    uint4* wsB = (uint4*)d_ws;   // needs 48*64*16 = 49152 B

    prep_weights<<<48, 64, 0, stream>>>(w0, w1, wsB);
    mpi_mlp<<<NRAYS, 256, 0, stream>>>(rays_o, rays_d, dgrid, k0g, ash,
                                       w0, b0, b1, w2, b2, wsB, out);
}